// Round 5
// baseline (561.836 us; speedup 1.0000x reference)
//
#include <hip/hip_runtime.h>
#include <cmath>

#define NSLOPE 0.2f
#define BN_EPS 1e-5f

static __device__ __forceinline__ float lrelu(float v) { return v > 0.f ? v : NSLOPE * v; }

static __device__ __forceinline__ float wmax64(float v) {
#pragma unroll
  for (int off = 32; off; off >>= 1) v = fmaxf(v, __shfl_xor(v, off));
  return v;
}
static __device__ __forceinline__ float wsum64(float v) {
#pragma unroll
  for (int off = 32; off; off >>= 1) v += __shfl_xor(v, off);
  return v;
}
static __device__ __forceinline__ float rlf(float v, int j) {
  return __int_as_float(__builtin_amdgcn_readlane(__float_as_int(v), j));
}

// ---------------------------------------------------------------- init
__global__ void k_init(int* __restrict__ cursor, int N) {
  int i = blockIdx.x * blockDim.x + threadIdx.x;
  int stride = gridDim.x * blockDim.x;
  for (int j = i; j < N; j += stride) cursor[j] = 1;  // self-loop count
}

// in-degree histogram + graph starts via sorted-boundary writes
__global__ void k_hist(const int* __restrict__ edst, int E, int* __restrict__ cursor,
                       const int* __restrict__ batch, int N, int* __restrict__ gstart) {
  int i = blockIdx.x * blockDim.x + threadIdx.x;
  int stride = gridDim.x * blockDim.x;
  int total = E > N ? E : N;
  for (int j = i; j < total; j += stride) {
    if (j < E) atomicAdd(&cursor[edst[j]], 1);
    if (j < N) {
      int b = batch[j];
      if (j == 0) {
        for (int g = 0; g <= b; ++g) gstart[g] = 0;
      } else {
        int pb = batch[j - 1];
        if (pb != b)
          for (int g = pb + 1; g <= b; ++g) gstart[g] = j;
      }
      if (j == N - 1)
        for (int g = b + 1; g <= 64; ++g) gstart[g] = N;
    }
  }
}

// ---------------------------------------------------------------- scan (3-phase)
__global__ __launch_bounds__(512) void k_scanA(const int* __restrict__ cnt, int N,
                                               int* __restrict__ partials) {
  int t = threadIdx.x;
  int i = blockIdx.x * 512 + t;
  int v = (i < N) ? cnt[i] : 0;
#pragma unroll
  for (int off = 32; off; off >>= 1) v += __shfl_xor(v, off);
  __shared__ int red[8];
  if ((t & 63) == 0) red[t >> 6] = v;
  __syncthreads();
  if (t == 0) {
    int s = 0;
#pragma unroll
    for (int w = 0; w < 8; ++w) s += red[w];
    partials[blockIdx.x] = s;
  }
}

__global__ void k_scanB(int* __restrict__ partials, int nchunks,
                        int* __restrict__ offsets, int N) {
  if (threadIdx.x == 0 && blockIdx.x == 0) {
    int run = 0;
    for (int b = 0; b < nchunks; ++b) { int t = partials[b]; partials[b] = run; run += t; }
    offsets[N] = run;
  }
}

__global__ __launch_bounds__(512) void k_scanC(int* __restrict__ cursor, int* __restrict__ offsets,
                                               const int* __restrict__ partials, int N) {
  __shared__ int s[512];
  int t = threadIdx.x;
  int i = blockIdx.x * 512 + t;
  int c = (i < N) ? cursor[i] : 0;
  s[t] = c;
  __syncthreads();
  for (int off = 1; off < 512; off <<= 1) {
    int v = (t >= off) ? s[t - off] : 0;
    __syncthreads();
    s[t] += v;
    __syncthreads();
  }
  if (i < N) {
    int excl = s[t] - c + partials[blockIdx.x];
    offsets[i] = excl;
    cursor[i] = excl;  // scatter cursor
  }
}

__global__ void k_scatter(const int* __restrict__ esrc, const int* __restrict__ edst,
                          int E, int N, int* __restrict__ cursor, int* __restrict__ srcs) {
  int i = blockIdx.x * blockDim.x + threadIdx.x;
  int stride = gridDim.x * blockDim.x;
  int total = E + N;
  for (int j = i; j < total; j += stride) {
    int s, d;
    if (j < E) { s = esrc[j]; d = edst[j]; } else { s = j - E; d = j - E; }
    int pos = atomicAdd(&cursor[d], 1);
    srcs[pos] = s;
  }
}

// ---------------------------------------------------------------- q = W @ a  (per-head projected score vectors)
__global__ void k_prep(const float* __restrict__ W1, const float* __restrict__ as1,
                       const float* __restrict__ ad1, const float* __restrict__ W2,
                       const float* __restrict__ as2, const float* __restrict__ ad2,
                       float* __restrict__ q1s, float* __restrict__ q1d,
                       float* __restrict__ q2s, float* __restrict__ q2d) {
  int t = threadIdx.x;
  if (t < 32) {  // q1[k][h], k<8, h<4
    int k = t >> 2, h = t & 3;
    float s = 0.f, d = 0.f;
    for (int c = 0; c < 32; ++c) {
      float w = W1[k * 128 + h * 32 + c];
      s = fmaf(w, as1[h * 32 + c], s);
      d = fmaf(w, ad1[h * 32 + c], d);
    }
    q1s[t] = s; q1d[t] = d;
  }
  for (int i = t; i < 512; i += 256) {  // q2[k][h], k<128, h<4
    int k = i >> 2, h = i & 3;
    float s = 0.f, d = 0.f;
    for (int c = 0; c < 64; ++c) {
      float w = W2[k * 256 + h * 64 + c];
      s = fmaf(w, as2[h * 64 + c], s);
      d = fmaf(w, ad2[h * 64 + c], d);
    }
    q2s[i] = s; q2d[i] = d;
  }
}

// ---------------------------------------------------------------- layer-1 scores from x
__global__ __launch_bounds__(256) void k_s1(const float* __restrict__ x,
                                            const float* __restrict__ q1s,
                                            const float* __restrict__ q1d,
                                            float* __restrict__ ssrc, float* __restrict__ sdst,
                                            int N) {
  __shared__ float qs[32], qd[32];
  int t = threadIdx.x;
  if (t < 32) { qs[t] = q1s[t]; qd[t] = q1d[t]; }
  __syncthreads();
  for (int n = blockIdx.x * 256 + t; n < N; n += gridDim.x * 256) {
    float4 x0 = *(const float4*)&x[n * 8];
    float4 x1 = *(const float4*)&x[n * 8 + 4];
    float xs[8] = {x0.x, x0.y, x0.z, x0.w, x1.x, x1.y, x1.z, x1.w};
    float4 rs = make_float4(0.f, 0.f, 0.f, 0.f);
    float4 rd = make_float4(0.f, 0.f, 0.f, 0.f);
#pragma unroll
    for (int k = 0; k < 8; ++k) {
      rs.x = fmaf(xs[k], qs[k * 4 + 0], rs.x);
      rs.y = fmaf(xs[k], qs[k * 4 + 1], rs.y);
      rs.z = fmaf(xs[k], qs[k * 4 + 2], rs.z);
      rs.w = fmaf(xs[k], qs[k * 4 + 3], rs.w);
      rd.x = fmaf(xs[k], qd[k * 4 + 0], rd.x);
      rd.y = fmaf(xs[k], qd[k * 4 + 1], rd.y);
      rd.z = fmaf(xs[k], qd[k * 4 + 2], rd.z);
      rd.w = fmaf(xs[k], qd[k * 4 + 3], rd.w);
    }
    *(float4*)&ssrc[n * 4] = rs;
    *(float4*)&sdst[n * 4] = rd;
  }
}

// ---------------------------------------------------------------- layer-1 aggregation, wave-per-node (x-space, 32B/edge)
__global__ __launch_bounds__(256) void k_agg1(const float* __restrict__ x,
                                              const float* __restrict__ ssrc,
                                              const float* __restrict__ sdst,
                                              const int* __restrict__ offsets,
                                              const int* __restrict__ srcs,
                                              float* __restrict__ agg /*[N][4][8]*/, int N) {
  int wid = threadIdx.x >> 6, l = threadIdx.x & 63;
  int n = blockIdx.x * 4 + wid;
  if (n >= N) return;
  int beg = offsets[n], deg = offsets[n + 1] - beg;
  float4 sd = *(const float4*)&sdst[n * 4];
  float m0 = -INFINITY, m1 = -INFINITY, m2 = -INFINITY, m3 = -INFINITY;
  float d0 = 0.f, d1 = 0.f, d2 = 0.f, d3 = 0.f;
  float acc[4][8];
#pragma unroll
  for (int h = 0; h < 4; ++h)
#pragma unroll
    for (int k = 0; k < 8; ++k) acc[h][k] = 0.f;
  const float4* x4 = (const float4*)x;
  for (int c0 = 0; c0 < deg; c0 += 64) {
    int e = c0 + l;
    bool act = e < deg;
    int s = act ? srcs[beg + e] : 0;
    float4 sv = *(const float4*)&ssrc[s * 4];
    float v0 = act ? lrelu(sv.x + sd.x) : -INFINITY;
    float v1 = act ? lrelu(sv.y + sd.y) : -INFINITY;
    float v2 = act ? lrelu(sv.z + sd.z) : -INFINITY;
    float v3 = act ? lrelu(sv.w + sd.w) : -INFINITY;
    float nm0 = fmaxf(m0, wmax64(v0)), nm1 = fmaxf(m1, wmax64(v1));
    float nm2 = fmaxf(m2, wmax64(v2)), nm3 = fmaxf(m3, wmax64(v3));
    float sc0 = expf(m0 - nm0), sc1 = expf(m1 - nm1);
    float sc2 = expf(m2 - nm2), sc3 = expf(m3 - nm3);
    m0 = nm0; m1 = nm1; m2 = nm2; m3 = nm3;
    float ev0 = act ? expf(v0 - m0) : 0.f;
    float ev1 = act ? expf(v1 - m1) : 0.f;
    float ev2 = act ? expf(v2 - m2) : 0.f;
    float ev3 = act ? expf(v3 - m3) : 0.f;
    d0 = d0 * sc0 + wsum64(ev0);
    d1 = d1 * sc1 + wsum64(ev1);
    d2 = d2 * sc2 + wsum64(ev2);
    d3 = d3 * sc3 + wsum64(ev3);
    float scl[4] = {sc0, sc1, sc2, sc3};
    float evs[4] = {ev0, ev1, ev2, ev3};
#pragma unroll
    for (int h = 0; h < 4; ++h)
#pragma unroll
      for (int k = 0; k < 8; ++k) acc[h][k] *= scl[h];
    float4 xa = x4[(size_t)s * 2];
    float4 xb = x4[(size_t)s * 2 + 1];
    float xs[8] = {xa.x, xa.y, xa.z, xa.w, xb.x, xb.y, xb.z, xb.w};
#pragma unroll
    for (int h = 0; h < 4; ++h)
#pragma unroll
      for (int k = 0; k < 8; ++k) acc[h][k] = fmaf(evs[h], xs[k], acc[h][k]);
  }
#pragma unroll
  for (int h = 0; h < 4; ++h)
#pragma unroll
    for (int k = 0; k < 8; ++k) {
#pragma unroll
      for (int off = 32; off; off >>= 1) acc[h][k] += __shfl_xor(acc[h][k], off);
    }
  if (l == 0) {
    float dd[4] = {d0, d1, d2, d3};
#pragma unroll
    for (int h = 0; h < 4; ++h) {
      float inv = 1.0f / dd[h];
      float4 oA = make_float4(acc[h][0] * inv, acc[h][1] * inv, acc[h][2] * inv, acc[h][3] * inv);
      float4 oB = make_float4(acc[h][4] * inv, acc[h][5] * inv, acc[h][6] * inv, acc[h][7] * inv);
      *(float4*)&agg[n * 32 + h * 8] = oA;
      *(float4*)&agg[n * 32 + h * 8 + 4] = oB;
    }
  }
}

// ---------------------------------------------------------------- out1 = agg1 @ W1 (per head) + b1, fused BN1 partial stats
__global__ __launch_bounds__(128) void k_post1(const float* __restrict__ agg,
                                               const float* __restrict__ W1,
                                               const float* __restrict__ b1,
                                               float* __restrict__ o1,
                                               float* __restrict__ part, int N) {
  int t = threadIdx.x;
  __shared__ float ag[32];
  float bb = b1[t];
  float wc[8];
#pragma unroll
  for (int k = 0; k < 8; ++k) wc[k] = W1[k * 128 + t];
  int h = t >> 5;
  float s = 0.f, s2 = 0.f;
  for (int n = blockIdx.x; n < N; n += gridDim.x) {
    if (t < 32) ag[t] = agg[n * 32 + t];
    __syncthreads();
    float v = bb;
#pragma unroll
    for (int k = 0; k < 8; ++k) v = fmaf(ag[h * 8 + k], wc[k], v);
    o1[(size_t)n * 128 + t] = v;
    s += v; s2 += v * v;
    __syncthreads();
  }
  part[(size_t)blockIdx.x * 256 + t] = s;
  part[(size_t)blockIdx.x * 256 + 128 + t] = s2;
}

// ---------------------------------------------------------------- parallel partial reduce: stat[j] = sum_b part[b*TWO_F + j]
template <int NB, int TWO_F>
__global__ __launch_bounds__(256) void k_bnreduce2(const float* __restrict__ part,
                                                   float* __restrict__ stat) {
  int j = blockIdx.x, t = threadIdx.x;
  float s = 0.f;
  for (int b = t; b < NB; b += 256) s += part[(size_t)b * TWO_F + j];
#pragma unroll
  for (int off = 32; off; off >>= 1) s += __shfl_xor(s, off);
  __shared__ float red[4];
  if ((t & 63) == 0) red[t >> 6] = s;
  __syncthreads();
  if (t == 0) stat[j] = (red[0] + red[1]) + (red[2] + red[3]);
}

// ---------------------------------------------------------------- BN1 apply + ELU + fused layer-2 scores
__global__ __launch_bounds__(128) void k_bns2(float* __restrict__ xio,
                                              const float* __restrict__ sum,
                                              const float* __restrict__ sq,
                                              const float* __restrict__ gamma,
                                              const float* __restrict__ beta,
                                              const float* __restrict__ q2s,
                                              const float* __restrict__ q2d,
                                              float* __restrict__ ssrc2,
                                              float* __restrict__ sdst2, int N) {
  int t = threadIdx.x;
  float mean = sum[t] * (1.0f / N);
  float var = sq[t] * (1.0f / N) - mean * mean;
  float inv = rsqrtf(var + BN_EPS);
  float ga = gamma[t], be = beta[t];
  float4 qs = *(const float4*)&q2s[t * 4];
  float4 qd = *(const float4*)&q2d[t * 4];
  __shared__ float redv[2][8];
  int wid = t >> 6, lane = t & 63;
  for (int r = blockIdx.x; r < N; r += gridDim.x) {
    float v = xio[(size_t)r * 128 + t];
    float y = ga * ((v - mean) * inv) + be;
    y = y > 0.f ? y : expm1f(y);
    xio[(size_t)r * 128 + t] = y;
    float p0 = y * qs.x, p1 = y * qs.y, p2 = y * qs.z, p3 = y * qs.w;
    float d0 = y * qd.x, d1 = y * qd.y, d2 = y * qd.z, d3 = y * qd.w;
#pragma unroll
    for (int off = 32; off; off >>= 1) {
      p0 += __shfl_xor(p0, off); p1 += __shfl_xor(p1, off);
      p2 += __shfl_xor(p2, off); p3 += __shfl_xor(p3, off);
      d0 += __shfl_xor(d0, off); d1 += __shfl_xor(d1, off);
      d2 += __shfl_xor(d2, off); d3 += __shfl_xor(d3, off);
    }
    if (lane == 0) {
      redv[wid][0] = p0; redv[wid][1] = p1; redv[wid][2] = p2; redv[wid][3] = p3;
      redv[wid][4] = d0; redv[wid][5] = d1; redv[wid][6] = d2; redv[wid][7] = d3;
    }
    __syncthreads();
    if (t < 8) {
      float s = redv[0][t] + redv[1][t];
      if (t < 4) ssrc2[r * 4 + t] = s;
      else sdst2[r * 4 + (t - 4)] = s;
    }
    __syncthreads();
  }
}

// ---------------------------------------------------------------- layer-2 aggregation, wave-per-node (a1-space, 512B/edge)
__global__ __launch_bounds__(256) void k_agg2(const float* __restrict__ a1,
                                              const float* __restrict__ ssrc,
                                              const float* __restrict__ sdst,
                                              const int* __restrict__ offsets,
                                              const int* __restrict__ srcs,
                                              float* __restrict__ agg /*[4][N][128]*/, int N) {
  int wid = threadIdx.x >> 6, l = threadIdx.x & 63;
  int n = blockIdx.x * 4 + wid;
  if (n >= N) return;
  int beg = offsets[n], deg = offsets[n + 1] - beg;
  float4 sd = *(const float4*)&sdst[n * 4];
  float m0 = -INFINITY, m1 = -INFINITY, m2 = -INFINITY, m3 = -INFINITY;
  float d0 = 0.f, d1 = 0.f, d2 = 0.f, d3 = 0.f;
  float2 ac0 = {0.f, 0.f}, ac1 = {0.f, 0.f}, ac2 = {0.f, 0.f}, ac3 = {0.f, 0.f};
  const float2* a1v = (const float2*)a1;
  for (int c0 = 0; c0 < deg; c0 += 64) {
    int e = c0 + l;
    bool act = e < deg;
    int s = act ? srcs[beg + e] : 0;
    float4 sv = *(const float4*)&ssrc[s * 4];
    float v0 = act ? lrelu(sv.x + sd.x) : -INFINITY;
    float v1 = act ? lrelu(sv.y + sd.y) : -INFINITY;
    float v2 = act ? lrelu(sv.z + sd.z) : -INFINITY;
    float v3 = act ? lrelu(sv.w + sd.w) : -INFINITY;
    float nm0 = fmaxf(m0, wmax64(v0)), nm1 = fmaxf(m1, wmax64(v1));
    float nm2 = fmaxf(m2, wmax64(v2)), nm3 = fmaxf(m3, wmax64(v3));
    float sc0 = expf(m0 - nm0), sc1 = expf(m1 - nm1);
    float sc2 = expf(m2 - nm2), sc3 = expf(m3 - nm3);
    m0 = nm0; m1 = nm1; m2 = nm2; m3 = nm3;
    float ev0 = act ? expf(v0 - m0) : 0.f;
    float ev1 = act ? expf(v1 - m1) : 0.f;
    float ev2 = act ? expf(v2 - m2) : 0.f;
    float ev3 = act ? expf(v3 - m3) : 0.f;
    d0 = d0 * sc0 + wsum64(ev0);
    d1 = d1 * sc1 + wsum64(ev1);
    d2 = d2 * sc2 + wsum64(ev2);
    d3 = d3 * sc3 + wsum64(ev3);
    ac0.x *= sc0; ac0.y *= sc0; ac1.x *= sc1; ac1.y *= sc1;
    ac2.x *= sc2; ac2.y *= sc2; ac3.x *= sc3; ac3.y *= sc3;
    int cn = min(64, deg - c0);
    for (int j = 0; j < cn; ++j) {
      int sj = __builtin_amdgcn_readlane(s, j);
      float w0 = rlf(ev0, j), w1 = rlf(ev1, j), w2 = rlf(ev2, j), w3 = rlf(ev3, j);
      float2 v = a1v[(size_t)sj * 64 + l];
      ac0.x = fmaf(w0, v.x, ac0.x); ac0.y = fmaf(w0, v.y, ac0.y);
      ac1.x = fmaf(w1, v.x, ac1.x); ac1.y = fmaf(w1, v.y, ac1.y);
      ac2.x = fmaf(w2, v.x, ac2.x); ac2.y = fmaf(w2, v.y, ac2.y);
      ac3.x = fmaf(w3, v.x, ac3.x); ac3.y = fmaf(w3, v.y, ac3.y);
    }
  }
  float2* ag = (float2*)agg;
  size_t pl = (size_t)N * 64;
  size_t base = (size_t)n * 64 + l;
  float i0 = 1.0f / d0, i1 = 1.0f / d1, i2 = 1.0f / d2, i3 = 1.0f / d3;
  ag[base] = make_float2(ac0.x * i0, ac0.y * i0);
  ag[pl + base] = make_float2(ac1.x * i1, ac1.y * i1);
  ag[2 * pl + base] = make_float2(ac2.x * i2, ac2.y * i2);
  ag[3 * pl + base] = make_float2(ac3.x * i3, ac3.y * i3);
}

// ---------------------------------------------------------------- out2 = per-head [N,128]@[128,64] + b2, fused BN2 partial stats
__global__ __launch_bounds__(256) void k_post2(const float* __restrict__ agg,
                                               const float* __restrict__ W2,
                                               const float* __restrict__ b2,
                                               float* __restrict__ out,
                                               float* __restrict__ part, int N) {
  __shared__ float As[128][64];
  __shared__ float Bs[128][64];
  int h = blockIdx.y;
  int m0 = blockIdx.x * 64;
  int tid = threadIdx.x;
  const float* Ap = agg + (size_t)h * N * 128;
  {
    int ml = tid & 63, kg = tid >> 6;
    const float* arow = Ap + (size_t)(m0 + ml) * 128;
    bool rok = (m0 + ml) < N;
#pragma unroll
    for (int it = 0; it < 8; ++it) {
      int k4 = kg + 4 * it;
      float4 v = rok ? *(const float4*)(arow + k4 * 4) : make_float4(0.f, 0.f, 0.f, 0.f);
      As[k4 * 4 + 0][ml] = v.x;
      As[k4 * 4 + 1][ml] = v.y;
      As[k4 * 4 + 2][ml] = v.z;
      As[k4 * 4 + 3][ml] = v.w;
    }
  }
  {
    int c4 = tid & 15, k0 = tid >> 4;  // 16 row-groups
    for (int k = k0; k < 128; k += 16) {
      float4 v = *(const float4*)&W2[(size_t)k * 256 + h * 64 + c4 * 4];
      *(float4*)&Bs[k][c4 * 4] = v;
    }
  }
  __syncthreads();
  int tx = tid & 15, ty = tid >> 4;
  float acc[4][4];
#pragma unroll
  for (int r = 0; r < 4; ++r)
#pragma unroll
    for (int c = 0; c < 4; ++c) acc[r][c] = 0.f;
#pragma unroll 2
  for (int k = 0; k < 128; ++k) {
    float4 a4 = *(const float4*)&As[k][ty * 4];
    float4 b4 = *(const float4*)&Bs[k][tx * 4];
    float av[4] = {a4.x, a4.y, a4.z, a4.w};
    float bv[4] = {b4.x, b4.y, b4.z, b4.w};
#pragma unroll
    for (int r = 0; r < 4; ++r)
#pragma unroll
      for (int c = 0; c < 4; ++c) acc[r][c] = fmaf(av[r], bv[c], acc[r][c]);
  }
  float4 bb = *(const float4*)&b2[h * 64 + tx * 4];
  float ps[4] = {0.f, 0.f, 0.f, 0.f};
  float pq[4] = {0.f, 0.f, 0.f, 0.f};
#pragma unroll
  for (int r = 0; r < 4; ++r) {
    int row = m0 + ty * 4 + r;
    if (row < N) {
      float4 c4;
      c4.x = acc[r][0] + bb.x; c4.y = acc[r][1] + bb.y;
      c4.z = acc[r][2] + bb.z; c4.w = acc[r][3] + bb.w;
      *(float4*)&out[(size_t)row * 256 + h * 64 + tx * 4] = c4;
      ps[0] += c4.x; pq[0] += c4.x * c4.x;
      ps[1] += c4.y; pq[1] += c4.y * c4.y;
      ps[2] += c4.z; pq[2] += c4.z * c4.z;
      ps[3] += c4.w; pq[3] += c4.w * c4.w;
    }
  }
  __syncthreads();
  float* red = &As[0][0];  // reuse 8192-float LDS
#pragma unroll
  for (int c = 0; c < 4; ++c) {
    red[ty * 64 + tx * 4 + c] = ps[c];
    red[1024 + ty * 64 + tx * 4 + c] = pq[c];
  }
  __syncthreads();
  if (tid < 128) {
    int isq = tid >> 6, col = tid & 63;
    float s = 0.f;
#pragma unroll
    for (int w = 0; w < 16; ++w) s += red[isq * 1024 + w * 64 + col];
    part[((size_t)blockIdx.x * 4 + h) * 128 + isq * 64 + col] = s;
  }
}

// ---------------------------------------------------------------- reduce post2 partials: stat[512] = {sum2[256], sq2[256]}
__global__ __launch_bounds__(256) void k_bnredpost(const float* __restrict__ part, int nmb,
                                                   float* __restrict__ stat) {
  int j = blockIdx.x;  // 0..511
  int isq = j >> 8, col = j & 255;
  int h = col >> 6, cw = col & 63;
  int t = threadIdx.x;
  float s = 0.f;
  for (int mb = t; mb < nmb; mb += 256) s += part[((size_t)mb * 4 + h) * 128 + isq * 64 + cw];
#pragma unroll
  for (int off = 32; off; off >>= 1) s += __shfl_xor(s, off);
  __shared__ float red[4];
  if ((t & 63) == 0) red[t >> 6] = s;
  __syncthreads();
  if (t == 0) stat[j] = (red[0] + red[1]) + (red[2] + red[3]);
}

// ---------------------------------------------------------------- fused BN2-apply + ELU + mean-pool partials
__global__ __launch_bounds__(256) void k_poolbn(const float* __restrict__ o2,
                                                const int* __restrict__ gstart,
                                                const float* __restrict__ sum,
                                                const float* __restrict__ sq,
                                                const float* __restrict__ gamma,
                                                const float* __restrict__ beta,
                                                float* __restrict__ part, int N) {
  int g = blockIdx.x, by = blockIdx.y, t = threadIdx.x;
  float mean = sum[t] * (1.0f / N);
  float var = sq[t] * (1.0f / N) - mean * mean;
  float inv = rsqrtf(var + BN_EPS);
  float ga = gamma[t], be = beta[t];
  int r0 = gstart[g], r1 = gstart[g + 1];
  float s = 0.f;
  for (int base = r0 + by * 128; base < r1; base += 16 * 128) {
    int lim = min(r1, base + 128);
    for (int r = base; r < lim; ++r) {
      float v = o2[(size_t)r * 256 + t];
      float y = ga * ((v - mean) * inv) + be;
      s += (y > 0.f ? y : expm1f(y));
    }
  }
  part[((size_t)g * 16 + by) * 256 + t] = s;
}

// ---------------------------------------------------------------- fused FC head (+ pool reduce/divide)
__global__ __launch_bounds__(256) void k_head(const float* __restrict__ poolpart,
                                              const int* __restrict__ gstart,
                                              const float* __restrict__ w1, const float* __restrict__ b1,
                                              const float* __restrict__ w2, const float* __restrict__ b2,
                                              const float* __restrict__ w3, const float* __restrict__ b3,
                                              float* __restrict__ out) {
  __shared__ float p[256], z1[128], z2[64];
  int g = blockIdx.x, t = threadIdx.x;
  float s0 = 0.f;
#pragma unroll
  for (int b = 0; b < 16; ++b) s0 += poolpart[((size_t)g * 16 + b) * 256 + t];
  float cnt = (float)(gstart[g + 1] - gstart[g]);
  p[t] = s0 / fmaxf(cnt, 1.0f);
  __syncthreads();
  if (t < 128) {
    float s = b1[t];
    for (int k = 0; k < 256; ++k) s = fmaf(p[k], w1[k * 128 + t], s);
    z1[t] = fmaxf(s, 0.f);
  }
  __syncthreads();
  if (t < 64) {
    float s = b2[t];
    for (int k = 0; k < 128; ++k) s = fmaf(z1[k], w2[k * 64 + t], s);
    z2[t] = fmaxf(s, 0.f);
  }
  __syncthreads();
  if (t < 64) {
    float s = z2[t] * w3[t];
#pragma unroll
    for (int off = 32; off; off >>= 1) s += __shfl_xor(s, off);
    if (t == 0) out[g] = s + b3[0];
  }
}

// ---------------------------------------------------------------- launch
extern "C" void kernel_launch(void* const* d_in, const int* in_sizes, int n_in,
                              void* d_out, int out_size, void* d_ws, size_t ws_size,
                              hipStream_t stream) {
  const float* x    = (const float*)d_in[0];
  const int*   eidx = (const int*)d_in[1];
  const int*   batch= (const int*)d_in[2];
  const float* W1   = (const float*)d_in[3];
  const float* as1  = (const float*)d_in[4];
  const float* ad1  = (const float*)d_in[5];
  const float* b1   = (const float*)d_in[6];
  const float* g1   = (const float*)d_in[7];
  const float* be1  = (const float*)d_in[8];
  const float* W2   = (const float*)d_in[9];
  const float* as2  = (const float*)d_in[10];
  const float* ad2  = (const float*)d_in[11];
  const float* b2   = (const float*)d_in[12];
  const float* g2   = (const float*)d_in[13];
  const float* be2  = (const float*)d_in[14];
  const float* fc1w = (const float*)d_in[15];
  const float* fc1b = (const float*)d_in[16];
  const float* fc2w = (const float*)d_in[17];
  const float* fc2b = (const float*)d_in[18];
  const float* fc3w = (const float*)d_in[19];
  const float* fc3b = (const float*)d_in[20];
  float* out = (float*)d_out;
  (void)n_in; (void)out_size; (void)ws_size;

  int N = in_sizes[0] / 8;
  int E = in_sizes[1] / 2;
  const int* esrc = eidx;
  const int* edst = eidx + E;
  int nchunks = (N + 511) / 512;
  int nmb = (N + 63) / 64;

  char* w = (char*)d_ws;
  auto take = [&](size_t bytes) -> char* {
    char* r = w;
    w += (bytes + 255) & ~(size_t)255;
    return r;
  };
  int*   offsets = (int*)take(4 * (size_t)(N + 1));
  int*   cursor  = (int*)take(4 * (size_t)N);
  int*   srcs    = (int*)take(4 * (size_t)(E + N));
  int*   partials= (int*)take(4 * (size_t)nchunks);
  int*   gstart  = (int*)take(4 * 65);
  float* bnstat  = (float*)take(4 * 1024);
  float* bnpart  = (float*)take(4 * 524288);
  float* pp2     = (float*)take(4 * (size_t)nmb * 512);
  float* poolpart= (float*)take(4 * 64 * 16 * 256);
  float* q1s     = (float*)take(4 * 32);
  float* q1d     = (float*)take(4 * 32);
  float* q2s     = (float*)take(4 * 512);
  float* q2d     = (float*)take(4 * 512);
  float* ssrc1   = (float*)take(16 * (size_t)N);
  float* sdst1   = (float*)take(16 * (size_t)N);
  float* ssrc2   = (float*)take(16 * (size_t)N);
  float* sdst2   = (float*)take(16 * (size_t)N);
  float* agg1    = (float*)take(4 * (size_t)N * 32);
  float* o1      = (float*)take(4 * (size_t)N * 128);   // -> a1 in place
  float* agg2    = (float*)take(4 * (size_t)N * 512);   // [4][N][128]
  float* o2      = (float*)take(4 * (size_t)N * 256);

  float* sum1 = bnstat;       float* sq1 = bnstat + 128;
  float* sum2 = bnstat + 256; float* sq2 = bnstat + 512;

  k_init<<<196, 256, 0, stream>>>(cursor, N);
  k_prep<<<1, 256, 0, stream>>>(W1, as1, ad1, W2, as2, ad2, q1s, q1d, q2s, q2d);
  k_hist<<<2048, 256, 0, stream>>>(edst, E, cursor, batch, N, gstart);
  k_scanA<<<nchunks, 512, 0, stream>>>(cursor, N, partials);
  k_scanB<<<1, 1, 0, stream>>>(partials, nchunks, offsets, N);
  k_scanC<<<nchunks, 512, 0, stream>>>(cursor, offsets, partials, N);
  k_scatter<<<2048, 256, 0, stream>>>(esrc, edst, E, N, cursor, srcs);

  k_s1<<<256, 256, 0, stream>>>(x, q1s, q1d, ssrc1, sdst1, N);
  k_agg1<<<(N + 3) / 4, 256, 0, stream>>>(x, ssrc1, sdst1, offsets, srcs, agg1, N);
  k_post1<<<2048, 128, 0, stream>>>(agg1, W1, b1, o1, bnpart, N);
  k_bnreduce2<2048, 256><<<256, 256, 0, stream>>>(bnpart, bnstat);
  k_bns2<<<1024, 128, 0, stream>>>(o1, sum1, sq1, g1, be1, q2s, q2d, ssrc2, sdst2, N);

  k_agg2<<<(N + 3) / 4, 256, 0, stream>>>(o1, ssrc2, sdst2, offsets, srcs, agg2, N);
  k_post2<<<dim3(nmb, 4), 256, 0, stream>>>(agg2, W2, b2, o2, pp2, N);
  k_bnredpost<<<512, 256, 0, stream>>>(pp2, nmb, sum2);

  k_poolbn<<<dim3(64, 16), 256, 0, stream>>>(o2, gstart, sum2, sq2, g2, be2, poolpart, N);
  k_head<<<64, 256, 0, stream>>>(poolpart, gstart, fc1w, fc1b, fc2w, fc2b, fc3w, fc3b, out);
}

// Round 6
// 473.841 us; speedup vs baseline: 1.1857x; 1.1857x over previous
//
#include <hip/hip_runtime.h>
#include <cmath>

#define NSLOPE 0.2f
#define BN_EPS 1e-5f

static __device__ __forceinline__ float lrelu(float v) { return v > 0.f ? v : NSLOPE * v; }

static __device__ __forceinline__ float wmax64(float v) {
#pragma unroll
  for (int off = 32; off; off >>= 1) v = fmaxf(v, __shfl_xor(v, off));
  return v;
}
static __device__ __forceinline__ float wsum64(float v) {
#pragma unroll
  for (int off = 32; off; off >>= 1) v += __shfl_xor(v, off);
  return v;
}
static __device__ __forceinline__ float rlf(float v, int j) {
  return __int_as_float(__builtin_amdgcn_readlane(__float_as_int(v), j));
}

// ---------------------------------------------------------------- init
__global__ void k_init(int* __restrict__ cursor, int N) {
  int i = blockIdx.x * blockDim.x + threadIdx.x;
  int stride = gridDim.x * blockDim.x;
  for (int j = i; j < N; j += stride) cursor[j] = 1;  // self-loop count
}

// in-degree histogram + graph starts via sorted-boundary writes
__global__ void k_hist(const int* __restrict__ edst, int E, int* __restrict__ cursor,
                       const int* __restrict__ batch, int N, int* __restrict__ gstart) {
  int i = blockIdx.x * blockDim.x + threadIdx.x;
  int stride = gridDim.x * blockDim.x;
  int total = E > N ? E : N;
  for (int j = i; j < total; j += stride) {
    if (j < E) atomicAdd(&cursor[edst[j]], 1);
    if (j < N) {
      int b = batch[j];
      if (j == 0) {
        for (int g = 0; g <= b; ++g) gstart[g] = 0;
      } else {
        int pb = batch[j - 1];
        if (pb != b)
          for (int g = pb + 1; g <= b; ++g) gstart[g] = j;
      }
      if (j == N - 1)
        for (int g = b + 1; g <= 64; ++g) gstart[g] = N;
    }
  }
}

// ---------------------------------------------------------------- scan (3-phase)
__global__ __launch_bounds__(512) void k_scanA(const int* __restrict__ cnt, int N,
                                               int* __restrict__ partials) {
  int t = threadIdx.x;
  int i = blockIdx.x * 512 + t;
  int v = (i < N) ? cnt[i] : 0;
#pragma unroll
  for (int off = 32; off; off >>= 1) v += __shfl_xor(v, off);
  __shared__ int red[8];
  if ((t & 63) == 0) red[t >> 6] = v;
  __syncthreads();
  if (t == 0) {
    int s = 0;
#pragma unroll
    for (int w = 0; w < 8; ++w) s += red[w];
    partials[blockIdx.x] = s;
  }
}

__global__ void k_scanB(int* __restrict__ partials, int nchunks,
                        int* __restrict__ offsets, int N) {
  if (threadIdx.x == 0 && blockIdx.x == 0) {
    int run = 0;
    for (int b = 0; b < nchunks; ++b) { int t = partials[b]; partials[b] = run; run += t; }
    offsets[N] = run;
  }
}

__global__ __launch_bounds__(512) void k_scanC(int* __restrict__ cursor, int* __restrict__ offsets,
                                               const int* __restrict__ partials, int N) {
  __shared__ int s[512];
  int t = threadIdx.x;
  int i = blockIdx.x * 512 + t;
  int c = (i < N) ? cursor[i] : 0;
  s[t] = c;
  __syncthreads();
  for (int off = 1; off < 512; off <<= 1) {
    int v = (t >= off) ? s[t - off] : 0;
    __syncthreads();
    s[t] += v;
    __syncthreads();
  }
  if (i < N) {
    int excl = s[t] - c + partials[blockIdx.x];
    offsets[i] = excl;
    cursor[i] = excl;  // scatter cursor
  }
}

__global__ void k_scatter(const int* __restrict__ esrc, const int* __restrict__ edst,
                          int E, int N, int* __restrict__ cursor, int* __restrict__ srcs) {
  int i = blockIdx.x * blockDim.x + threadIdx.x;
  int stride = gridDim.x * blockDim.x;
  int total = E + N;
  for (int j = i; j < total; j += stride) {
    int s, d;
    if (j < E) { s = esrc[j]; d = edst[j]; } else { s = j - E; d = j - E; }
    int pos = atomicAdd(&cursor[d], 1);
    srcs[pos] = s;
  }
}

// ---------------------------------------------------------------- q = W @ a  (per-head projected score vectors)
__global__ void k_prep(const float* __restrict__ W1, const float* __restrict__ as1,
                       const float* __restrict__ ad1, const float* __restrict__ W2,
                       const float* __restrict__ as2, const float* __restrict__ ad2,
                       float* __restrict__ q1s, float* __restrict__ q1d,
                       float* __restrict__ q2s, float* __restrict__ q2d) {
  int t = threadIdx.x;
  if (t < 32) {  // q1[k][h], k<8, h<4
    int k = t >> 2, h = t & 3;
    float s = 0.f, d = 0.f;
    for (int c = 0; c < 32; ++c) {
      float w = W1[k * 128 + h * 32 + c];
      s = fmaf(w, as1[h * 32 + c], s);
      d = fmaf(w, ad1[h * 32 + c], d);
    }
    q1s[t] = s; q1d[t] = d;
  }
  for (int i = t; i < 512; i += 256) {  // q2[k][h], k<128, h<4
    int k = i >> 2, h = i & 3;
    float s = 0.f, d = 0.f;
    for (int c = 0; c < 64; ++c) {
      float w = W2[k * 256 + h * 64 + c];
      s = fmaf(w, as2[h * 64 + c], s);
      d = fmaf(w, ad2[h * 64 + c], d);
    }
    q2s[i] = s; q2d[i] = d;
  }
}

// ---------------------------------------------------------------- layer-1 scores from x
__global__ __launch_bounds__(256) void k_s1(const float* __restrict__ x,
                                            const float* __restrict__ q1s,
                                            const float* __restrict__ q1d,
                                            float* __restrict__ ssrc, float* __restrict__ sdst,
                                            int N) {
  __shared__ float qs[32], qd[32];
  int t = threadIdx.x;
  if (t < 32) { qs[t] = q1s[t]; qd[t] = q1d[t]; }
  __syncthreads();
  for (int n = blockIdx.x * 256 + t; n < N; n += gridDim.x * 256) {
    float4 x0 = *(const float4*)&x[n * 8];
    float4 x1 = *(const float4*)&x[n * 8 + 4];
    float xs[8] = {x0.x, x0.y, x0.z, x0.w, x1.x, x1.y, x1.z, x1.w};
    float4 rs = make_float4(0.f, 0.f, 0.f, 0.f);
    float4 rd = make_float4(0.f, 0.f, 0.f, 0.f);
#pragma unroll
    for (int k = 0; k < 8; ++k) {
      rs.x = fmaf(xs[k], qs[k * 4 + 0], rs.x);
      rs.y = fmaf(xs[k], qs[k * 4 + 1], rs.y);
      rs.z = fmaf(xs[k], qs[k * 4 + 2], rs.z);
      rs.w = fmaf(xs[k], qs[k * 4 + 3], rs.w);
      rd.x = fmaf(xs[k], qd[k * 4 + 0], rd.x);
      rd.y = fmaf(xs[k], qd[k * 4 + 1], rd.y);
      rd.z = fmaf(xs[k], qd[k * 4 + 2], rd.z);
      rd.w = fmaf(xs[k], qd[k * 4 + 3], rd.w);
    }
    *(float4*)&ssrc[n * 4] = rs;
    *(float4*)&sdst[n * 4] = rd;
  }
}

// ---------------------------------------------------------------- layer-1 aggregation, thread-per-node, exact 2-pass softmax
__global__ __launch_bounds__(64) void k_agg1(const float* __restrict__ x,
                                             const float* __restrict__ ssrc,
                                             const float* __restrict__ sdst,
                                             const int* __restrict__ offsets,
                                             const int* __restrict__ srcs,
                                             float* __restrict__ agg /*[N][4][8]*/, int N) {
  int n = blockIdx.x * 64 + threadIdx.x;
  if (n >= N) return;
  int beg = offsets[n], end = offsets[n + 1];
  float4 sd = *(const float4*)&sdst[n * 4];
  float m0 = -INFINITY, m1 = -INFINITY, m2 = -INFINITY, m3 = -INFINITY;
  // pass 1: per-head max
  for (int e = beg; e < end; ++e) {
    int s = srcs[e];
    float4 sv = *(const float4*)&ssrc[s * 4];
    m0 = fmaxf(m0, lrelu(sv.x + sd.x));
    m1 = fmaxf(m1, lrelu(sv.y + sd.y));
    m2 = fmaxf(m2, lrelu(sv.z + sd.z));
    m3 = fmaxf(m3, lrelu(sv.w + sd.w));
  }
  // pass 2: exp + accumulate
  float d0 = 0.f, d1 = 0.f, d2 = 0.f, d3 = 0.f;
  float acc[4][8];
#pragma unroll
  for (int h = 0; h < 4; ++h)
#pragma unroll
    for (int k = 0; k < 8; ++k) acc[h][k] = 0.f;
  const float4* x4 = (const float4*)x;
  for (int e = beg; e < end; ++e) {
    int s = srcs[e];
    float4 sv = *(const float4*)&ssrc[s * 4];
    float w0 = expf(lrelu(sv.x + sd.x) - m0);
    float w1 = expf(lrelu(sv.y + sd.y) - m1);
    float w2 = expf(lrelu(sv.z + sd.z) - m2);
    float w3 = expf(lrelu(sv.w + sd.w) - m3);
    d0 += w0; d1 += w1; d2 += w2; d3 += w3;
    float4 xa = x4[(size_t)s * 2];
    float4 xb = x4[(size_t)s * 2 + 1];
    float xs[8] = {xa.x, xa.y, xa.z, xa.w, xb.x, xb.y, xb.z, xb.w};
    float ws[4] = {w0, w1, w2, w3};
#pragma unroll
    for (int h = 0; h < 4; ++h)
#pragma unroll
      for (int k = 0; k < 8; ++k) acc[h][k] = fmaf(ws[h], xs[k], acc[h][k]);
  }
  float dd[4] = {d0, d1, d2, d3};
#pragma unroll
  for (int h = 0; h < 4; ++h) {
    float inv = 1.0f / dd[h];
    float4 oA = make_float4(acc[h][0] * inv, acc[h][1] * inv, acc[h][2] * inv, acc[h][3] * inv);
    float4 oB = make_float4(acc[h][4] * inv, acc[h][5] * inv, acc[h][6] * inv, acc[h][7] * inv);
    *(float4*)&agg[n * 32 + h * 8] = oA;
    *(float4*)&agg[n * 32 + h * 8 + 4] = oB;
  }
}

// ---------------------------------------------------------------- out1 = agg1 @ W1 (per head) + b1, fused BN1 partial stats
__global__ __launch_bounds__(128) void k_post1(const float* __restrict__ agg,
                                               const float* __restrict__ W1,
                                               const float* __restrict__ b1,
                                               float* __restrict__ o1,
                                               float* __restrict__ part, int N) {
  int t = threadIdx.x;
  __shared__ float ag[32];
  float bb = b1[t];
  float wc[8];
#pragma unroll
  for (int k = 0; k < 8; ++k) wc[k] = W1[k * 128 + t];
  int h = t >> 5;
  float s = 0.f, s2 = 0.f;
  for (int n = blockIdx.x; n < N; n += gridDim.x) {
    if (t < 32) ag[t] = agg[n * 32 + t];
    __syncthreads();
    float v = bb;
#pragma unroll
    for (int k = 0; k < 8; ++k) v = fmaf(ag[h * 8 + k], wc[k], v);
    o1[(size_t)n * 128 + t] = v;
    s += v; s2 += v * v;
    __syncthreads();
  }
  part[(size_t)blockIdx.x * 256 + t] = s;
  part[(size_t)blockIdx.x * 256 + 128 + t] = s2;
}

// ---------------------------------------------------------------- parallel partial reduce: stat[j] = sum_b part[b*TWO_F + j]
template <int NB, int TWO_F>
__global__ __launch_bounds__(256) void k_bnreduce2(const float* __restrict__ part,
                                                   float* __restrict__ stat) {
  int j = blockIdx.x, t = threadIdx.x;
  float s = 0.f;
  for (int b = t; b < NB; b += 256) s += part[(size_t)b * TWO_F + j];
#pragma unroll
  for (int off = 32; off; off >>= 1) s += __shfl_xor(s, off);
  __shared__ float red[4];
  if ((t & 63) == 0) red[t >> 6] = s;
  __syncthreads();
  if (t == 0) stat[j] = (red[0] + red[1]) + (red[2] + red[3]);
}

// ---------------------------------------------------------------- BN1 apply + ELU + fused layer-2 scores
__global__ __launch_bounds__(128) void k_bns2(float* __restrict__ xio,
                                              const float* __restrict__ sum,
                                              const float* __restrict__ sq,
                                              const float* __restrict__ gamma,
                                              const float* __restrict__ beta,
                                              const float* __restrict__ q2s,
                                              const float* __restrict__ q2d,
                                              float* __restrict__ ssrc2,
                                              float* __restrict__ sdst2, int N) {
  int t = threadIdx.x;
  float mean = sum[t] * (1.0f / N);
  float var = sq[t] * (1.0f / N) - mean * mean;
  float inv = rsqrtf(var + BN_EPS);
  float ga = gamma[t], be = beta[t];
  float4 qs = *(const float4*)&q2s[t * 4];
  float4 qd = *(const float4*)&q2d[t * 4];
  __shared__ float redv[2][8];
  int wid = t >> 6, lane = t & 63;
  for (int r = blockIdx.x; r < N; r += gridDim.x) {
    float v = xio[(size_t)r * 128 + t];
    float y = ga * ((v - mean) * inv) + be;
    y = y > 0.f ? y : expm1f(y);
    xio[(size_t)r * 128 + t] = y;
    float p0 = y * qs.x, p1 = y * qs.y, p2 = y * qs.z, p3 = y * qs.w;
    float d0 = y * qd.x, d1 = y * qd.y, d2 = y * qd.z, d3 = y * qd.w;
#pragma unroll
    for (int off = 32; off; off >>= 1) {
      p0 += __shfl_xor(p0, off); p1 += __shfl_xor(p1, off);
      p2 += __shfl_xor(p2, off); p3 += __shfl_xor(p3, off);
      d0 += __shfl_xor(d0, off); d1 += __shfl_xor(d1, off);
      d2 += __shfl_xor(d2, off); d3 += __shfl_xor(d3, off);
    }
    if (lane == 0) {
      redv[wid][0] = p0; redv[wid][1] = p1; redv[wid][2] = p2; redv[wid][3] = p3;
      redv[wid][4] = d0; redv[wid][5] = d1; redv[wid][6] = d2; redv[wid][7] = d3;
    }
    __syncthreads();
    if (t < 8) {
      float s = redv[0][t] + redv[1][t];
      if (t < 4) ssrc2[r * 4 + t] = s;
      else sdst2[r * 4 + (t - 4)] = s;
    }
    __syncthreads();
  }
}

// ---------------------------------------------------------------- layer-2 aggregation, wave-per-node (a1-space, 512B/edge)
__global__ __launch_bounds__(256) void k_agg2(const float* __restrict__ a1,
                                              const float* __restrict__ ssrc,
                                              const float* __restrict__ sdst,
                                              const int* __restrict__ offsets,
                                              const int* __restrict__ srcs,
                                              float* __restrict__ agg /*[4][N][128]*/, int N) {
  int wid = threadIdx.x >> 6, l = threadIdx.x & 63;
  int n = blockIdx.x * 4 + wid;
  if (n >= N) return;
  int beg = offsets[n], deg = offsets[n + 1] - beg;
  float4 sd = *(const float4*)&sdst[n * 4];
  float m0 = -INFINITY, m1 = -INFINITY, m2 = -INFINITY, m3 = -INFINITY;
  float d0 = 0.f, d1 = 0.f, d2 = 0.f, d3 = 0.f;
  float2 ac0 = {0.f, 0.f}, ac1 = {0.f, 0.f}, ac2 = {0.f, 0.f}, ac3 = {0.f, 0.f};
  const float2* a1v = (const float2*)a1;
  for (int c0 = 0; c0 < deg; c0 += 64) {
    int e = c0 + l;
    bool act = e < deg;
    int s = act ? srcs[beg + e] : 0;
    float4 sv = *(const float4*)&ssrc[s * 4];
    float v0 = act ? lrelu(sv.x + sd.x) : -INFINITY;
    float v1 = act ? lrelu(sv.y + sd.y) : -INFINITY;
    float v2 = act ? lrelu(sv.z + sd.z) : -INFINITY;
    float v3 = act ? lrelu(sv.w + sd.w) : -INFINITY;
    float nm0 = fmaxf(m0, wmax64(v0)), nm1 = fmaxf(m1, wmax64(v1));
    float nm2 = fmaxf(m2, wmax64(v2)), nm3 = fmaxf(m3, wmax64(v3));
    float sc0 = expf(m0 - nm0), sc1 = expf(m1 - nm1);
    float sc2 = expf(m2 - nm2), sc3 = expf(m3 - nm3);
    m0 = nm0; m1 = nm1; m2 = nm2; m3 = nm3;
    float ev0 = act ? expf(v0 - m0) : 0.f;
    float ev1 = act ? expf(v1 - m1) : 0.f;
    float ev2 = act ? expf(v2 - m2) : 0.f;
    float ev3 = act ? expf(v3 - m3) : 0.f;
    d0 = d0 * sc0 + wsum64(ev0);
    d1 = d1 * sc1 + wsum64(ev1);
    d2 = d2 * sc2 + wsum64(ev2);
    d3 = d3 * sc3 + wsum64(ev3);
    ac0.x *= sc0; ac0.y *= sc0; ac1.x *= sc1; ac1.y *= sc1;
    ac2.x *= sc2; ac2.y *= sc2; ac3.x *= sc3; ac3.y *= sc3;
    int cn = min(64, deg - c0);
    for (int j = 0; j < cn; ++j) {
      int sj = __builtin_amdgcn_readlane(s, j);
      float w0 = rlf(ev0, j), w1 = rlf(ev1, j), w2 = rlf(ev2, j), w3 = rlf(ev3, j);
      float2 v = a1v[(size_t)sj * 64 + l];
      ac0.x = fmaf(w0, v.x, ac0.x); ac0.y = fmaf(w0, v.y, ac0.y);
      ac1.x = fmaf(w1, v.x, ac1.x); ac1.y = fmaf(w1, v.y, ac1.y);
      ac2.x = fmaf(w2, v.x, ac2.x); ac2.y = fmaf(w2, v.y, ac2.y);
      ac3.x = fmaf(w3, v.x, ac3.x); ac3.y = fmaf(w3, v.y, ac3.y);
    }
  }
  float2* ag = (float2*)agg;
  size_t pl = (size_t)N * 64;
  size_t base = (size_t)n * 64 + l;
  float i0 = 1.0f / d0, i1 = 1.0f / d1, i2 = 1.0f / d2, i3 = 1.0f / d3;
  ag[base] = make_float2(ac0.x * i0, ac0.y * i0);
  ag[pl + base] = make_float2(ac1.x * i1, ac1.y * i1);
  ag[2 * pl + base] = make_float2(ac2.x * i2, ac2.y * i2);
  ag[3 * pl + base] = make_float2(ac3.x * i3, ac3.y * i3);
}

// ---------------------------------------------------------------- out2 = per-head [N,128]@[128,64] + b2, fused BN2 partial stats
__global__ __launch_bounds__(256) void k_post2(const float* __restrict__ agg,
                                               const float* __restrict__ W2,
                                               const float* __restrict__ b2,
                                               float* __restrict__ out,
                                               float* __restrict__ part, int N) {
  __shared__ float As[128][64];
  __shared__ float Bs[128][64];
  int h = blockIdx.y;
  int m0 = blockIdx.x * 64;
  int tid = threadIdx.x;
  const float* Ap = agg + (size_t)h * N * 128;
  {
    int ml = tid & 63, kg = tid >> 6;
    const float* arow = Ap + (size_t)(m0 + ml) * 128;
    bool rok = (m0 + ml) < N;
#pragma unroll
    for (int it = 0; it < 8; ++it) {
      int k4 = kg + 4 * it;
      float4 v = rok ? *(const float4*)(arow + k4 * 4) : make_float4(0.f, 0.f, 0.f, 0.f);
      As[k4 * 4 + 0][ml] = v.x;
      As[k4 * 4 + 1][ml] = v.y;
      As[k4 * 4 + 2][ml] = v.z;
      As[k4 * 4 + 3][ml] = v.w;
    }
  }
  {
    int c4 = tid & 15, k0 = tid >> 4;  // 16 row-groups
    for (int k = k0; k < 128; k += 16) {
      float4 v = *(const float4*)&W2[(size_t)k * 256 + h * 64 + c4 * 4];
      *(float4*)&Bs[k][c4 * 4] = v;
    }
  }
  __syncthreads();
  int tx = tid & 15, ty = tid >> 4;
  float acc[4][4];
#pragma unroll
  for (int r = 0; r < 4; ++r)
#pragma unroll
    for (int c = 0; c < 4; ++c) acc[r][c] = 0.f;
#pragma unroll 2
  for (int k = 0; k < 128; ++k) {
    float4 a4 = *(const float4*)&As[k][ty * 4];
    float4 b4 = *(const float4*)&Bs[k][tx * 4];
    float av[4] = {a4.x, a4.y, a4.z, a4.w};
    float bv[4] = {b4.x, b4.y, b4.z, b4.w};
#pragma unroll
    for (int r = 0; r < 4; ++r)
#pragma unroll
      for (int c = 0; c < 4; ++c) acc[r][c] = fmaf(av[r], bv[c], acc[r][c]);
  }
  float4 bb = *(const float4*)&b2[h * 64 + tx * 4];
  float ps[4] = {0.f, 0.f, 0.f, 0.f};
  float pq[4] = {0.f, 0.f, 0.f, 0.f};
#pragma unroll
  for (int r = 0; r < 4; ++r) {
    int row = m0 + ty * 4 + r;
    if (row < N) {
      float4 c4;
      c4.x = acc[r][0] + bb.x; c4.y = acc[r][1] + bb.y;
      c4.z = acc[r][2] + bb.z; c4.w = acc[r][3] + bb.w;
      *(float4*)&out[(size_t)row * 256 + h * 64 + tx * 4] = c4;
      ps[0] += c4.x; pq[0] += c4.x * c4.x;
      ps[1] += c4.y; pq[1] += c4.y * c4.y;
      ps[2] += c4.z; pq[2] += c4.z * c4.z;
      ps[3] += c4.w; pq[3] += c4.w * c4.w;
    }
  }
  __syncthreads();
  float* red = &As[0][0];  // reuse 8192-float LDS
#pragma unroll
  for (int c = 0; c < 4; ++c) {
    red[ty * 64 + tx * 4 + c] = ps[c];
    red[1024 + ty * 64 + tx * 4 + c] = pq[c];
  }
  __syncthreads();
  if (tid < 128) {
    int isq = tid >> 6, col = tid & 63;
    float s = 0.f;
#pragma unroll
    for (int w = 0; w < 16; ++w) s += red[isq * 1024 + w * 64 + col];
    part[((size_t)blockIdx.x * 4 + h) * 128 + isq * 64 + col] = s;
  }
}

// ---------------------------------------------------------------- reduce post2 partials: stat[512] = {sum2[256], sq2[256]}
__global__ __launch_bounds__(256) void k_bnredpost(const float* __restrict__ part, int nmb,
                                                   float* __restrict__ stat) {
  int j = blockIdx.x;  // 0..511
  int isq = j >> 8, col = j & 255;
  int h = col >> 6, cw = col & 63;
  int t = threadIdx.x;
  float s = 0.f;
  for (int mb = t; mb < nmb; mb += 256) s += part[((size_t)mb * 4 + h) * 128 + isq * 64 + cw];
#pragma unroll
  for (int off = 32; off; off >>= 1) s += __shfl_xor(s, off);
  __shared__ float red[4];
  if ((t & 63) == 0) red[t >> 6] = s;
  __syncthreads();
  if (t == 0) stat[j] = (red[0] + red[1]) + (red[2] + red[3]);
}

// ---------------------------------------------------------------- fused BN2-apply + ELU + mean-pool partials
__global__ __launch_bounds__(256) void k_poolbn(const float* __restrict__ o2,
                                                const int* __restrict__ gstart,
                                                const float* __restrict__ sum,
                                                const float* __restrict__ sq,
                                                const float* __restrict__ gamma,
                                                const float* __restrict__ beta,
                                                float* __restrict__ part, int N) {
  int g = blockIdx.x, by = blockIdx.y, t = threadIdx.x;
  float mean = sum[t] * (1.0f / N);
  float var = sq[t] * (1.0f / N) - mean * mean;
  float inv = rsqrtf(var + BN_EPS);
  float ga = gamma[t], be = beta[t];
  int r0 = gstart[g], r1 = gstart[g + 1];
  float s = 0.f;
  for (int base = r0 + by * 128; base < r1; base += 16 * 128) {
    int lim = min(r1, base + 128);
    for (int r = base; r < lim; ++r) {
      float v = o2[(size_t)r * 256 + t];
      float y = ga * ((v - mean) * inv) + be;
      s += (y > 0.f ? y : expm1f(y));
    }
  }
  part[((size_t)g * 16 + by) * 256 + t] = s;
}

// ---------------------------------------------------------------- fused FC head (+ pool reduce/divide)
__global__ __launch_bounds__(256) void k_head(const float* __restrict__ poolpart,
                                              const int* __restrict__ gstart,
                                              const float* __restrict__ w1, const float* __restrict__ b1,
                                              const float* __restrict__ w2, const float* __restrict__ b2,
                                              const float* __restrict__ w3, const float* __restrict__ b3,
                                              float* __restrict__ out) {
  __shared__ float p[256], z1[128], z2[64];
  int g = blockIdx.x, t = threadIdx.x;
  float s0 = 0.f;
#pragma unroll
  for (int b = 0; b < 16; ++b) s0 += poolpart[((size_t)g * 16 + b) * 256 + t];
  float cnt = (float)(gstart[g + 1] - gstart[g]);
  p[t] = s0 / fmaxf(cnt, 1.0f);
  __syncthreads();
  if (t < 128) {
    float s = b1[t];
    for (int k = 0; k < 256; ++k) s = fmaf(p[k], w1[k * 128 + t], s);
    z1[t] = fmaxf(s, 0.f);
  }
  __syncthreads();
  if (t < 64) {
    float s = b2[t];
    for (int k = 0; k < 128; ++k) s = fmaf(z1[k], w2[k * 64 + t], s);
    z2[t] = fmaxf(s, 0.f);
  }
  __syncthreads();
  if (t < 64) {
    float s = z2[t] * w3[t];
#pragma unroll
    for (int off = 32; off; off >>= 1) s += __shfl_xor(s, off);
    if (t == 0) out[g] = s + b3[0];
  }
}

// ---------------------------------------------------------------- launch
extern "C" void kernel_launch(void* const* d_in, const int* in_sizes, int n_in,
                              void* d_out, int out_size, void* d_ws, size_t ws_size,
                              hipStream_t stream) {
  const float* x    = (const float*)d_in[0];
  const int*   eidx = (const int*)d_in[1];
  const int*   batch= (const int*)d_in[2];
  const float* W1   = (const float*)d_in[3];
  const float* as1  = (const float*)d_in[4];
  const float* ad1  = (const float*)d_in[5];
  const float* b1   = (const float*)d_in[6];
  const float* g1   = (const float*)d_in[7];
  const float* be1  = (const float*)d_in[8];
  const float* W2   = (const float*)d_in[9];
  const float* as2  = (const float*)d_in[10];
  const float* ad2  = (const float*)d_in[11];
  const float* b2   = (const float*)d_in[12];
  const float* g2   = (const float*)d_in[13];
  const float* be2  = (const float*)d_in[14];
  const float* fc1w = (const float*)d_in[15];
  const float* fc1b = (const float*)d_in[16];
  const float* fc2w = (const float*)d_in[17];
  const float* fc2b = (const float*)d_in[18];
  const float* fc3w = (const float*)d_in[19];
  const float* fc3b = (const float*)d_in[20];
  float* out = (float*)d_out;
  (void)n_in; (void)out_size; (void)ws_size;

  int N = in_sizes[0] / 8;
  int E = in_sizes[1] / 2;
  const int* esrc = eidx;
  const int* edst = eidx + E;
  int nchunks = (N + 511) / 512;
  int nmb = (N + 63) / 64;

  char* w = (char*)d_ws;
  auto take = [&](size_t bytes) -> char* {
    char* r = w;
    w += (bytes + 255) & ~(size_t)255;
    return r;
  };
  int*   offsets = (int*)take(4 * (size_t)(N + 1));
  int*   cursor  = (int*)take(4 * (size_t)N);
  int*   srcs    = (int*)take(4 * (size_t)(E + N));
  int*   partials= (int*)take(4 * (size_t)nchunks);
  int*   gstart  = (int*)take(4 * 65);
  float* bnstat  = (float*)take(4 * 1024);
  float* bnpart  = (float*)take(4 * 524288);
  float* pp2     = (float*)take(4 * (size_t)nmb * 512);
  float* poolpart= (float*)take(4 * 64 * 16 * 256);
  float* q1s     = (float*)take(4 * 32);
  float* q1d     = (float*)take(4 * 32);
  float* q2s     = (float*)take(4 * 512);
  float* q2d     = (float*)take(4 * 512);
  float* ssrc1   = (float*)take(16 * (size_t)N);
  float* sdst1   = (float*)take(16 * (size_t)N);
  float* ssrc2   = (float*)take(16 * (size_t)N);
  float* sdst2   = (float*)take(16 * (size_t)N);
  float* agg1    = (float*)take(4 * (size_t)N * 32);
  float* o1      = (float*)take(4 * (size_t)N * 128);   // -> a1 in place
  float* agg2    = (float*)take(4 * (size_t)N * 512);   // [4][N][128]
  float* o2      = (float*)take(4 * (size_t)N * 256);

  float* sum1 = bnstat;       float* sq1 = bnstat + 128;
  float* sum2 = bnstat + 256; float* sq2 = bnstat + 512;

  k_init<<<196, 256, 0, stream>>>(cursor, N);
  k_prep<<<1, 256, 0, stream>>>(W1, as1, ad1, W2, as2, ad2, q1s, q1d, q2s, q2d);
  k_hist<<<2048, 256, 0, stream>>>(edst, E, cursor, batch, N, gstart);
  k_scanA<<<nchunks, 512, 0, stream>>>(cursor, N, partials);
  k_scanB<<<1, 1, 0, stream>>>(partials, nchunks, offsets, N);
  k_scanC<<<nchunks, 512, 0, stream>>>(cursor, offsets, partials, N);
  k_scatter<<<2048, 256, 0, stream>>>(esrc, edst, E, N, cursor, srcs);

  k_s1<<<256, 256, 0, stream>>>(x, q1s, q1d, ssrc1, sdst1, N);
  k_agg1<<<(N + 63) / 64, 64, 0, stream>>>(x, ssrc1, sdst1, offsets, srcs, agg1, N);
  k_post1<<<2048, 128, 0, stream>>>(agg1, W1, b1, o1, bnpart, N);
  k_bnreduce2<2048, 256><<<256, 256, 0, stream>>>(bnpart, bnstat);
  k_bns2<<<1024, 128, 0, stream>>>(o1, sum1, sq1, g1, be1, q2s, q2d, ssrc2, sdst2, N);

  k_agg2<<<(N + 3) / 4, 256, 0, stream>>>(o1, ssrc2, sdst2, offsets, srcs, agg2, N);
  k_post2<<<dim3(nmb, 4), 256, 0, stream>>>(agg2, W2, b2, o2, pp2, N);
  k_bnredpost<<<512, 256, 0, stream>>>(pp2, nmb, sum2);

  k_poolbn<<<dim3(64, 16), 256, 0, stream>>>(o2, gstart, sum2, sq2, g2, be2, poolpart, N);
  k_head<<<64, 256, 0, stream>>>(poolpart, gstart, fc1w, fc1b, fc2w, fc2b, fc3w, fc3b, out);
}